// Round 4
// baseline (1203.211 us; speedup 1.0000x reference)
//
#include <hip/hip_runtime.h>
#include <hip/hip_bf16.h>
#include <math.h>

#define NUM_EMB 32
#define ADIM 32
#define HID 1024
#define BB 128
#define TT 64
#define MAXT 80   // max tasks: sum ceil(c_i/2) <= 64 + 16 = 80

typedef __attribute__((ext_vector_type(8))) __bf16 bf16x8;
typedef __attribute__((ext_vector_type(4))) float floatx4;

// ---------- K0: counting sort + same-cat pairing into task list ----------
__global__ void task_kernel(const int* __restrict__ cats, int4* __restrict__ tasks) {
  __shared__ int cnt[NUM_EMB];
  __shared__ int pos[NUM_EMB];
  __shared__ int pv[BB];
  int tid = threadIdx.x;
  if (tid < NUM_EMB) cnt[tid] = 0;
  __syncthreads();
  if (tid < BB) atomicAdd(&cnt[cats[tid]], 1);
  __syncthreads();
  if (tid == 0) {
    int run = 0;
    for (int c = 0; c < NUM_EMB; ++c) { pos[c] = run; run += cnt[c]; }
  }
  __syncthreads();
  if (tid < BB) {
    int p = atomicAdd(&pos[cats[tid]], 1);
    pv[p] = tid;
  }
  __syncthreads();
  if (tid == 0) {
    int t = 0, off = 0;
    for (int c = 0; c < NUM_EMB; ++c) {
      for (int i = 0; i < cnt[c]; i += 2) {
        int b0 = pv[off + i];
        int b1 = (i + 1 < cnt[c]) ? pv[off + i + 1] : -1;
        tasks[t++] = make_int4(b0, b1, c, 0);
      }
      off += cnt[c];
    }
    for (; t < MAXT; ++t) tasks[t] = make_int4(-1, -1, 0, 0);
  }
}

// ---------- K1: GEMM1 (fp32, K=32) + sinusoidal tau -> x2 bf16 ----------
__global__ __launch_bounds__(256) void embed_kernel(
    const float* __restrict__ actions, const float* __restrict__ timesteps,
    const float* __restrict__ W1w, const float* __restrict__ W1b,
    const int* __restrict__ cats, __bf16* __restrict__ x2) {
  const int b = blockIdx.y;
  const int t0 = blockIdx.x * 16;
  const int cat = cats[b];
  const int tid = threadIdx.x;

  __shared__ float act[16][ADIM];
  {
    int row = tid >> 5, k = tid & 31;
    act[row][k] = actions[((size_t)(b * TT + t0 + row)) * ADIM + k];
    act[row + 8][k] = actions[((size_t)(b * TT + t0 + row + 8)) * ADIM + k];
  }
  __syncthreads();

  const float* W = W1w + (size_t)cat * ADIM * HID;
  float acc[4][16];
#pragma unroll
  for (int ii = 0; ii < 4; ++ii) {
    float bv = W1b[cat * HID + tid + ii * 256];
#pragma unroll
    for (int tt = 0; tt < 16; ++tt) acc[ii][tt] = bv;
  }
  for (int k = 0; k < ADIM; ++k) {
#pragma unroll
    for (int ii = 0; ii < 4; ++ii) {
      float w = W[k * HID + tid + ii * 256];
#pragma unroll
      for (int tt = 0; tt < 16; ++tt) acc[ii][tt] += act[tt][k] * w;
    }
  }
#pragma unroll
  for (int ii = 0; ii < 4; ++ii) {
    int hcol = tid + ii * 256;
#pragma unroll
    for (int tt = 0; tt < 16; ++tt)
      x2[((size_t)(b * TT + t0 + tt)) * 2048 + hcol] = (__bf16)acc[ii][tt];
  }
  float tb = timesteps[b];
  const float kLog = 9.210340371976184f;  // ln(10000)
#pragma unroll
  for (int ii = 0; ii < 4; ++ii) {
    int j = tid + ii * 256;
    int jj = (j < 512) ? j : (j - 512);
    float freq = tb * expf(-kLog * (float)jj * (1.0f / 512.0f));
    float v = (j < 512) ? sinf(freq) : cosf(freq);
    __bf16 hv = (__bf16)v;
#pragma unroll
    for (int tt = 0; tt < 16; ++tt)
      x2[((size_t)(b * TT + t0 + tt)) * 2048 + 1024 + j] = hv;
  }
}

// ---------- K2/K3: paired-category bf16 MFMA GEMM, 2-deep pipeline ----------
// M=128 (b0 rows 0..63, b1 rows 64..127), N=128, Kstep=32, 4 waves.
// Double-buffered LDS (one barrier per k-step) + 2-deep register FIFO:
//   step k: [frag reads LDS[p]] [issue loads k+2] [16 MFMA]
//           [cvt+write W[k+1],A[k+1] -> LDS[p^1]] [barrier]
// Loads issued at step k are consumed at the END of step k+1 (>1 full step
// in flight); no vmcnt(0) before any barrier. Stride-40 (80 B) rows: all
// b128 LDS accesses map 64 lanes onto 8 start-banks x 4-bank span (8-phase,
// conflict-free).
template <bool SILU, bool OUT_BF16, int K>
__global__ __launch_bounds__(256, 3) void gemm_kernel(
    const __bf16* __restrict__ A, const float* __restrict__ Wbase,
    const float* __restrict__ bias, const int4* __restrict__ tasks,
    void* __restrict__ Out) {
  const int4 task = tasks[blockIdx.y];
  const int b0 = task.x, b1s = task.y, cat = task.z;
  if (b0 < 0) return;
  const int b1 = (b1s >= 0) ? b1s : b0;
  const int nb = blockIdx.x * 128;
  const int tid = threadIdx.x;
  const int w = tid >> 6, lane = tid & 63, q = lane >> 4, r = lane & 15;

  __shared__ __attribute__((aligned(16))) __bf16 As[2][128 * 40];
  __shared__ __attribute__((aligned(16))) __bf16 Bs[2][128 * 40];

  const float* W = Wbase + (size_t)cat * K * HID + nb;
  const __bf16* A0 = A + (size_t)b0 * TT * K;
  const __bf16* A1 = A + (size_t)b1 * TT * K;

  floatx4 acc[8][2];
#pragma unroll
  for (int mt = 0; mt < 8; ++mt)
#pragma unroll
    for (int nt = 0; nt < 2; ++nt) acc[mt][nt] = (floatx4){0.f, 0.f, 0.f, 0.f};

  const int bn = tid & 127;  // B col -> LDS row (1 row/thread)
  const int bkq = tid >> 7;  // 0..1; octets {bkq, bkq+2}
  const int am = tid >> 2;   // 0..63 A row
  const int ac = tid & 3;    // 16B chunk in 32-k row

  float wv[2][16];
  uint4 av[2][2];

  auto loadW = [&](int kk, float* dst) {
#pragma unroll
    for (int i = 0; i < 2; ++i) {
      const float* Wp = W + (size_t)(kk + (bkq + 2 * i) * 8) * HID + bn;
#pragma unroll
      for (int j = 0; j < 8; ++j) dst[i * 8 + j] = Wp[(size_t)j * HID];
    }
  };
  auto loadA = [&](int kk, uint4* dst) {
    dst[0] = *reinterpret_cast<const uint4*>(A0 + (size_t)am * K + kk + ac * 8);
    dst[1] = *reinterpret_cast<const uint4*>(A1 + (size_t)am * K + kk + ac * 8);
  };
  auto stage = [&](const float* wsrc, const uint4* asrc, int buf) {
    *reinterpret_cast<uint4*>(&As[buf][am * 40 + ac * 8]) = asrc[0];
    *reinterpret_cast<uint4*>(&As[buf][(am + 64) * 40 + ac * 8]) = asrc[1];
#pragma unroll
    for (int i = 0; i < 2; ++i) {
      union { uint4 u; __bf16 h[8]; } t;
#pragma unroll
      for (int j = 0; j < 8; ++j) t.h[j] = (__bf16)wsrc[i * 8 + j];
      *reinterpret_cast<uint4*>(&Bs[buf][bn * 40 + (bkq + 2 * i) * 8]) = t.u;
    }
  };

  // prologue: W[0]/A[0] -> set0 -> LDS0; W[1]/A[1] -> set1 (in flight)
  loadW(0, wv[0]);
  loadA(0, av[0]);
  if (32 < K) { loadW(32, wv[1]); loadA(32, av[1]); }
  stage(wv[0], av[0], 0);
  __syncthreads();

  int s = 0;
  for (int k0 = 0; k0 < K; k0 += 32, s ^= 1) {
    const int p = s & 1;
    // 1. frag reads from LDS[p]
    bf16x8 bfrag[2], afrag[8];
#pragma unroll
    for (int nt = 0; nt < 2; ++nt)
      bfrag[nt] = *reinterpret_cast<const bf16x8*>(&Bs[p][(w * 32 + nt * 16 + r) * 40 + q * 8]);
#pragma unroll
    for (int mt = 0; mt < 8; ++mt)
      afrag[mt] = *reinterpret_cast<const bf16x8*>(&As[p][(mt * 16 + r) * 40 + q * 8]);
    // 2. issue loads for k0+64 into the just-freed set
    if (k0 + 64 < K) { loadW(k0 + 64, wv[p]); loadA(k0 + 64, av[p]); }
    // 3. MFMA
#pragma unroll
    for (int mt = 0; mt < 8; ++mt) {
      acc[mt][0] = __builtin_amdgcn_mfma_f32_16x16x32_bf16(afrag[mt], bfrag[0], acc[mt][0], 0, 0, 0);
      acc[mt][1] = __builtin_amdgcn_mfma_f32_16x16x32_bf16(afrag[mt], bfrag[1], acc[mt][1], 0, 0, 0);
    }
    // 4. stage k0+32 (loads issued one step ago) into LDS[p^1]
    if (k0 + 32 < K) stage(wv[p ^ 1], av[p ^ 1], p ^ 1);
    // 5. single barrier per step
    __syncthreads();
  }

  // epilogue: D row = q*4+rr (m), col = r (n)  [m89/m91-verified]
#pragma unroll
  for (int nt = 0; nt < 2; ++nt) {
    int col = nb + w * 32 + nt * 16 + r;
    float bvv = bias[cat * HID + col];
#pragma unroll
    for (int mt = 0; mt < 8; ++mt) {
      if (mt >= 4 && b1s < 0) break;
      int b = (mt < 4) ? b0 : b1;
#pragma unroll
      for (int rr = 0; rr < 4; ++rr) {
        int m = (mt & 3) * 16 + q * 4 + rr;
        float v = acc[mt][nt][rr] + bvv;
        if (SILU) v = v / (1.0f + expf(-v));
        size_t oidx = ((size_t)(b * TT + m)) * HID + col;
        if (OUT_BF16) ((__bf16*)Out)[oidx] = (__bf16)v;
        else ((float*)Out)[oidx] = v;
      }
    }
  }
}

// ---------- launcher ----------
extern "C" void kernel_launch(void* const* d_in, const int* in_sizes, int n_in,
                              void* d_out, int out_size, void* d_ws, size_t ws_size,
                              hipStream_t stream) {
  const float* actions = (const float*)d_in[0];
  const float* timesteps = (const float*)d_in[1];
  const float* W1w = (const float*)d_in[2];
  const float* W1b = (const float*)d_in[3];
  const float* W2w = (const float*)d_in[4];
  const float* W2b = (const float*)d_in[5];
  const float* W3w = (const float*)d_in[6];
  const float* W3b = (const float*)d_in[7];
  const int* cats = (const int*)d_in[8];
  float* out = (float*)d_out;

  char* ws = (char*)d_ws;
  __bf16* x2 = (__bf16*)ws;                       // 33,554,432 B
  __bf16* h = (__bf16*)(ws + 33554432);           // 16,777,216 B
  int4* tasks = (int4*)(ws + 33554432 + 16777216);

  task_kernel<<<1, 128, 0, stream>>>(cats, tasks);
  embed_kernel<<<dim3(4, BB), 256, 0, stream>>>(actions, timesteps, W1w, W1b, cats, x2);
  gemm_kernel<true, true, 2048><<<dim3(8, MAXT), 256, 0, stream>>>(x2, W2w, W2b, tasks, (void*)h);
  gemm_kernel<false, false, 1024><<<dim3(8, MAXT), 256, 0, stream>>>(h, W3w, W3b, tasks, (void*)out);
}